// Round 1
// baseline (174.618 us; speedup 1.0000x reference)
//
#include <hip/hip_runtime.h>
#include <stdint.h>

#define M_NODES 4001
#define NW 63            // ceil(4001/64) bitmask words per row
#define DIM 128
#define THRESH 0.04f
#define ADJ_ROWS 32
#define MAXJ 1024

// fv_0 = relu([loc, td] @ W0^T + b); also materialize combined locations array.
__global__ void fv0_kernel(const float* __restrict__ node_loc,
                           const float* __restrict__ td,
                           const float* __restrict__ depot,
                           const float* __restrict__ W0w,
                           const float* __restrict__ W0b,
                           float* __restrict__ locs,
                           float* __restrict__ fv0) {
    int i = blockIdx.x;        // node
    int d = threadIdx.x;       // embed dim
    float lx, ly, t;
    if (i == 0) { lx = depot[0]; ly = depot[1]; t = 0.f; }
    else { lx = node_loc[(i - 1) * 2]; ly = node_loc[(i - 1) * 2 + 1]; t = td[i - 1]; }
    if (d == 0) { locs[i * 2] = lx; locs[i * 2 + 1] = ly; }
    float v = fmaf(lx, W0w[d * 3 + 0], fmaf(ly, W0w[d * 3 + 1], fmaf(t, W0w[d * 3 + 2], W0b[d])));
    fv0[(size_t)i * DIM + d] = v > 0.f ? v : 0.f;
}

// A bitmask rows. Lane mapping: consecutive lanes -> consecutive rows (same word w)
// so the inner sloc[j] LDS read is a same-address broadcast (conflict-free).
__global__ void adj_kernel(const float* __restrict__ locs,
                           uint64_t* __restrict__ A) {
    __shared__ float2 sloc[M_NODES];
    for (int idx = threadIdx.x; idx < M_NODES; idx += blockDim.x)
        sloc[idx] = ((const float2*)locs)[idx];
    __syncthreads();
    int i0 = blockIdx.x * ADJ_ROWS;
    const int ntask = ADJ_ROWS * NW;   // 2016
    for (int t = threadIdx.x; t < ntask; t += blockDim.x) {
        int r = t & (ADJ_ROWS - 1);    // consecutive lanes -> consecutive rows
        int w = t >> 5;                // word index, uniform across adjacent lanes
        int i = i0 + r;
        if (i >= M_NODES) continue;
        float xi = sloc[i].x, yi = sloc[i].y;
        uint64_t m = 0;
        int jbase = w * 64;
        int jend = (jbase + 64 <= M_NODES) ? 64 : (M_NODES - jbase);
        for (int b = 0; b < jend; ++b) {
            float dx = xi - sloc[jbase + b].x;   // broadcast read
            float dy = yi - sloc[jbase + b].y;
            float d2 = fmaf(dx, dx, dy * dy);
            if (sqrtf(d2) <= THRESH) m |= (1ull << b);
        }
        A[(size_t)i * NW + w] = m;
    }
}

// fv_1[i] = sum_{j in N(i)} fv_0[j]  (bitmask iterate, wave-uniform)
__global__ void fv1_kernel(const uint64_t* __restrict__ A,
                           const float* __restrict__ fv0,
                           float* __restrict__ fv1) {
    __shared__ uint64_t row[NW];
    int i = blockIdx.x;
    if (threadIdx.x < NW) row[threadIdx.x] = A[(size_t)i * NW + threadIdx.x];
    __syncthreads();
    float acc = 0.f;
    for (int w = 0; w < NW; ++w) {
        uint64_t m = row[w];
        int base = w * 64;
        while (m) {
            int b = __builtin_ctzll(m);
            acc += fv0[(size_t)(base + b) * DIM + threadIdx.x];  // coalesced 512B
            m &= m - 1;
        }
    }
    fv1[(size_t)i * DIM + threadIdx.x] = acc;
}

// M2 row i = OR over j in N(i) of A row j. 64 threads; thread w owns word w.
__global__ void m2_kernel(const uint64_t* __restrict__ A,
                          uint64_t* __restrict__ M2) {
    __shared__ uint64_t row[NW];
    int i = blockIdx.x;
    int tid = threadIdx.x;
    if (tid < NW) row[tid] = A[(size_t)i * NW + tid];
    __syncthreads();
    uint64_t acc = 0;
    for (int w = 0; w < NW; ++w) {
        uint64_t m = row[w];
        int base = w * 64;
        while (m) {
            int b = __builtin_ctzll(m);
            int j = base + b;
            if (tid < NW) acc |= A[(size_t)j * NW + tid];  // coalesced 504B
            m &= m - 1;
        }
    }
    if (tid < NW) M2[(size_t)i * NW + tid] = acc;
}

// fv_2[i] = sum_{j in M2(i)} popcount(M2_i & A_j) * fv_1[j]
__global__ void fv2_kernel(const uint64_t* __restrict__ A,
                           const uint64_t* __restrict__ M2,
                           const float* __restrict__ fv1,
                           float* __restrict__ out) {
    __shared__ uint64_t m2row[NW];
    __shared__ int list[MAXJ];
    __shared__ float cnt[MAXJ];
    __shared__ int nj;
    int i = blockIdx.x;
    int tid = threadIdx.x;   // 128
    if (tid == 0) nj = 0;
    if (tid < NW) m2row[tid] = M2[(size_t)i * NW + tid];
    __syncthreads();
    // Phase A: enumerate j in M2(i)
    if (tid < NW) {
        uint64_t m = m2row[tid];
        int base = tid * 64;
        while (m) {
            int b = __builtin_ctzll(m);
            int p = atomicAdd(&nj, 1);
            if (p < MAXJ) list[p] = base + b;
            m &= m - 1;
        }
    }
    __syncthreads();
    int n = nj < MAXJ ? nj : MAXJ;
    // Phase B: per-pair popcount counts (integers -> exact in fp32)
    for (int l = tid; l < n; l += blockDim.x) {
        int j = list[l];
        const uint64_t* aj = A + (size_t)j * NW;
        int c = 0;
        for (int w = 0; w < NW; ++w) c += __popcll(m2row[w] & aj[w]);
        cnt[l] = (float)c;
    }
    __syncthreads();
    // Phase C: weighted sum of fv1 rows (coalesced 512B loads, L2-resident)
    float acc = 0.f;
    for (int l = 0; l < n; ++l)
        acc = fmaf(cnt[l], fv1[(size_t)list[l] * DIM + tid], acc);
    out[(size_t)i * DIM + tid] = acc;
}

extern "C" void kernel_launch(void* const* d_in, const int* in_sizes, int n_in,
                              void* d_out, int out_size, void* d_ws, size_t ws_size,
                              hipStream_t stream) {
    const float* node_loc = (const float*)d_in[0];  // [4000,2]
    const float* td       = (const float*)d_in[1];  // [4000,1]
    const float* depot    = (const float*)d_in[2];  // [1,2]
    const float* W0w      = (const float*)d_in[3];  // [128,3]
    const float* W0b      = (const float*)d_in[4];  // [128]
    float* out = (float*)d_out;                     // [4001,128]

    char* base = (char*)d_ws;
    size_t off = 0;
    auto carve = [&](size_t bytes) {
        char* p = base + off;
        off = (off + bytes + 511) & ~(size_t)511;
        return p;
    };
    float*    locs = (float*)   carve((size_t)M_NODES * 2 * sizeof(float));
    uint64_t* A    = (uint64_t*)carve((size_t)M_NODES * NW * sizeof(uint64_t));
    uint64_t* M2   = (uint64_t*)carve((size_t)M_NODES * NW * sizeof(uint64_t));
    float*    fv0  = (float*)   carve((size_t)M_NODES * DIM * sizeof(float));
    float*    fv1  = (float*)   carve((size_t)M_NODES * DIM * sizeof(float));
    // total ~8.2 MB of ws

    fv0_kernel<<<M_NODES, DIM, 0, stream>>>(node_loc, td, depot, W0w, W0b, locs, fv0);
    adj_kernel<<<(M_NODES + ADJ_ROWS - 1) / ADJ_ROWS, 256, 0, stream>>>(locs, A);
    fv1_kernel<<<M_NODES, DIM, 0, stream>>>(A, fv0, fv1);
    m2_kernel<<<M_NODES, 64, 0, stream>>>(A, M2);
    fv2_kernel<<<M_NODES, DIM, 0, stream>>>(A, M2, fv1, out);
}

// Round 2
// 169.553 us; speedup vs baseline: 1.0299x; 1.0299x over previous
//
#include <hip/hip_runtime.h>
#include <stdint.h>

#define M_NODES 4001
#define NW 63            // ceil(4001/64) bitmask words per row
#define DIM 128
#define THRESH 0.04f
#define MAXJ 1024        // cap on |M2(i)| (expected ~80)
#define MAXN1 256        // cap on |N(i)| (expected ~20)

// fv_0 = relu([loc, td] @ W0^T + b). Flat over (node, dim).
__global__ void fv0_kernel(const float* __restrict__ node_loc,
                           const float* __restrict__ td,
                           const float* __restrict__ depot,
                           const float* __restrict__ W0w,
                           const float* __restrict__ W0b,
                           float* __restrict__ fv0) {
    int idx = blockIdx.x * blockDim.x + threadIdx.x;
    if (idx >= M_NODES * DIM) return;
    int i = idx >> 7;          // node
    int d = idx & (DIM - 1);   // embed dim
    float lx, ly, t;
    if (i == 0) { lx = depot[0]; ly = depot[1]; t = 0.f; }
    else { lx = node_loc[(i - 1) * 2]; ly = node_loc[(i - 1) * 2 + 1]; t = td[i - 1]; }
    float v = fmaf(lx, W0w[d * 3 + 0], fmaf(ly, W0w[d * 3 + 1], fmaf(t, W0w[d * 3 + 2], W0b[d])));
    fv0[idx] = v > 0.f ? v : 0.f;
}

// Adjacency bitmask rows. One thread per (row i, word w) task:
//   blockIdx.x = row-group (256 rows), blockIdx.y = word w (block-uniform).
// 64 candidates for word w staged in 512B LDS; inner reads are wave-uniform
// broadcasts (conflict-free). Predicate matches numpy exactly:
// d2 = dx*dx + dy*dy (no fp contraction), sqrtf correctly rounded, <= 0.04f.
__global__ void adj_kernel(const float* __restrict__ node_loc,
                           const float* __restrict__ depot,
                           uint64_t* __restrict__ A) {
    __shared__ float2 cand[64];
    int w = blockIdx.y;
    int tid = threadIdx.x;
    if (tid < 64) {
        int j = w * 64 + tid;
        float2 c;
        if (j == 0) { c.x = depot[0]; c.y = depot[1]; }
        else if (j < M_NODES) { c.x = node_loc[(j - 1) * 2]; c.y = node_loc[(j - 1) * 2 + 1]; }
        else { c.x = 1e9f; c.y = 1e9f; }   // out-of-range bits stay 0
        cand[tid] = c;
    }
    int i = blockIdx.x * blockDim.x + tid;
    float xi = 0.f, yi = 0.f;
    if (i == 0) { xi = depot[0]; yi = depot[1]; }
    else if (i < M_NODES) { xi = node_loc[(i - 1) * 2]; yi = node_loc[(i - 1) * 2 + 1]; }
    __syncthreads();
    uint64_t m = 0;
#pragma unroll
    for (int b = 0; b < 64; ++b) {
#pragma clang fp contract(off)
        float dx = xi - cand[b].x;           // LDS broadcast read
        float dy = yi - cand[b].y;
        float xx = dx * dx;
        float yy = dy * dy;
        float d2 = xx + yy;
        if (sqrtf(d2) <= THRESH) m |= (1ull << b);
    }
    if (i < M_NODES) A[(size_t)i * NW + w] = m;
}

// fv_1[i] = sum_{j in N(i)} fv_0[j]  (bitmask iterate, wave-uniform)
__global__ void fv1_kernel(const uint64_t* __restrict__ A,
                           const float* __restrict__ fv0,
                           float* __restrict__ fv1) {
    __shared__ uint64_t row[NW];
    int i = blockIdx.x;
    if (threadIdx.x < NW) row[threadIdx.x] = A[(size_t)i * NW + threadIdx.x];
    __syncthreads();
    float acc = 0.f;
    for (int w = 0; w < NW; ++w) {
        uint64_t m = row[w];
        int base = w * 64;
        while (m) {
            int b = __builtin_ctzll(m);
            acc += fv0[(size_t)(base + b) * DIM + threadIdx.x];  // coalesced 512B
            m &= m - 1;
        }
    }
    fv1[(size_t)i * DIM + threadIdx.x] = acc;
}

// fv_2[i] = sum_{j in M2(i)} popcount(M2_i & A_j) * fv_1[j],
// with M2 row i computed in-block: OR of A rows over j in N(i).
// 256 threads.
__global__ void fv2_kernel(const uint64_t* __restrict__ A,
                           const float* __restrict__ fv1,
                           float* __restrict__ out) {
    __shared__ uint64_t arow[64];
    __shared__ uint64_t m2part[4][64];
    __shared__ uint64_t m2row[64];
    __shared__ int list1[MAXN1];
    __shared__ int list2[MAXJ];
    __shared__ float cnt[MAXJ];
    __shared__ float accbuf[DIM];
    __shared__ int nn1, nn2;

    int i = blockIdx.x;
    int tid = threadIdx.x;
    if (tid == 0) { nn1 = 0; nn2 = 0; }
    if (tid < 64) arow[tid] = (tid < NW) ? A[(size_t)i * NW + tid] : 0ull;
    __syncthreads();

    // enumerate N(i)
    if (tid < NW) {
        uint64_t m = arow[tid];
        int base = tid * 64;
        while (m) {
            int b = __builtin_ctzll(m);
            int p = atomicAdd(&nn1, 1);
            if (p < MAXN1) list1[p] = base + b;
            m &= m - 1;
        }
    }
    __syncthreads();
    int n1 = nn1 < MAXN1 ? nn1 : MAXN1;

    // M2 row i = OR over j in N(i) of A row j. 4 groups x 64 words.
    {
        int w = tid & 63, g = tid >> 6;
        uint64_t o = 0;
        for (int l = g; l < n1; l += 4)
            o |= (w < NW) ? A[(size_t)list1[l] * NW + w] : 0ull;   // coalesced 504B
        m2part[g][w] = o;
    }
    __syncthreads();
    if (tid < 64) m2row[tid] = m2part[0][tid] | m2part[1][tid] | m2part[2][tid] | m2part[3][tid];
    __syncthreads();

    // enumerate M2(i)
    if (tid < NW) {
        uint64_t m = m2row[tid];
        int base = tid * 64;
        while (m) {
            int b = __builtin_ctzll(m);
            int p = atomicAdd(&nn2, 1);
            if (p < MAXJ) list2[p] = base + b;
            m &= m - 1;
        }
    }
    __syncthreads();
    int n2 = nn2 < MAXJ ? nn2 : MAXJ;

    // per-pair counts: c_j = popcount(M2_i & A_j)  (exact integers in fp32)
    for (int l = tid; l < n2; l += 256) {
        int j = list2[l];
        const uint64_t* aj = A + (size_t)j * NW;
        int c = 0;
        for (int w = 0; w < NW; ++w) c += __popcll(m2row[w] & aj[w]);  // m2row broadcast
        cnt[l] = (float)c;
    }
    __syncthreads();

    // weighted sum of fv1 rows; 2 groups split the serial chain.
    int d = tid & (DIM - 1), g2 = tid >> 7;
    float acc = 0.f;
    for (int l = g2; l < n2; l += 2)
        acc = fmaf(cnt[l], fv1[(size_t)list2[l] * DIM + d], acc);   // coalesced 512B
    if (g2 == 1) accbuf[d] = acc;
    __syncthreads();
    if (g2 == 0) out[(size_t)i * DIM + d] = acc + accbuf[d];
}

extern "C" void kernel_launch(void* const* d_in, const int* in_sizes, int n_in,
                              void* d_out, int out_size, void* d_ws, size_t ws_size,
                              hipStream_t stream) {
    const float* node_loc = (const float*)d_in[0];  // [4000,2]
    const float* td       = (const float*)d_in[1];  // [4000,1]
    const float* depot    = (const float*)d_in[2];  // [1,2]
    const float* W0w      = (const float*)d_in[3];  // [128,3]
    const float* W0b      = (const float*)d_in[4];  // [128]
    float* out = (float*)d_out;                     // [4001,128]

    char* base = (char*)d_ws;
    size_t off = 0;
    auto carve = [&](size_t bytes) {
        char* p = base + off;
        off = (off + bytes + 511) & ~(size_t)511;
        return p;
    };
    uint64_t* A   = (uint64_t*)carve((size_t)M_NODES * NW * sizeof(uint64_t));
    float*    fv0 = (float*)   carve((size_t)M_NODES * DIM * sizeof(float));
    float*    fv1 = (float*)   carve((size_t)M_NODES * DIM * sizeof(float));

    fv0_kernel<<<(M_NODES * DIM + 255) / 256, 256, 0, stream>>>(node_loc, td, depot, W0w, W0b, fv0);
    dim3 agrid((M_NODES + 255) / 256, NW);
    adj_kernel<<<agrid, 256, 0, stream>>>(node_loc, depot, A);
    fv1_kernel<<<M_NODES, DIM, 0, stream>>>(A, fv0, fv1);
    fv2_kernel<<<M_NODES, 256, 0, stream>>>(A, fv1, out);
}

// Round 3
// 111.820 us; speedup vs baseline: 1.5616x; 1.5163x over previous
//
#include <hip/hip_runtime.h>
#include <stdint.h>

#define M_NODES 4001
#define NW 63            // ceil(4001/64) bitmask words per row
#define DIM 128
#define THRESH 0.04f
#define MAXJ 1024        // cap on |M2(i)| (expected ~80)
#define CAP 96           // cap on degree (expected ~21, Poisson tail < 1e-14)

// fv_0 = relu([loc, td] @ W0^T + b). Flat over (node, dim).
__global__ void fv0_kernel(const float* __restrict__ node_loc,
                           const float* __restrict__ td,
                           const float* __restrict__ depot,
                           const float* __restrict__ W0w,
                           const float* __restrict__ W0b,
                           float* __restrict__ fv0) {
    int idx = blockIdx.x * blockDim.x + threadIdx.x;
    if (idx >= M_NODES * DIM) return;
    int i = idx >> 7;          // node
    int d = idx & (DIM - 1);   // embed dim
    float lx, ly, t;
    if (i == 0) { lx = depot[0]; ly = depot[1]; t = 0.f; }
    else { lx = node_loc[(i - 1) * 2]; ly = node_loc[(i - 1) * 2 + 1]; t = td[i - 1]; }
    float v = fmaf(lx, W0w[d * 3 + 0], fmaf(ly, W0w[d * 3 + 1], fmaf(t, W0w[d * 3 + 2], W0b[d])));
    fv0[idx] = v > 0.f ? v : 0.f;
}

// Adjacency bitmask rows. blockIdx.x = row-group (256 rows), blockIdx.y = word w.
// 64 candidates staged in LDS; inner reads are wave-uniform broadcasts.
// Predicate matches numpy: d2 = dx*dx + dy*dy (no contraction), sqrtf, <= 0.04f.
__global__ void adj_kernel(const float* __restrict__ node_loc,
                           const float* __restrict__ depot,
                           uint64_t* __restrict__ A) {
    __shared__ float2 cand[64];
    int w = blockIdx.y;
    int tid = threadIdx.x;
    if (tid < 64) {
        int j = w * 64 + tid;
        float2 c;
        if (j == 0) { c.x = depot[0]; c.y = depot[1]; }
        else if (j < M_NODES) { c.x = node_loc[(j - 1) * 2]; c.y = node_loc[(j - 1) * 2 + 1]; }
        else { c.x = 1e9f; c.y = 1e9f; }
        cand[tid] = c;
    }
    int i = blockIdx.x * blockDim.x + tid;
    float xi = 0.f, yi = 0.f;
    if (i == 0) { xi = depot[0]; yi = depot[1]; }
    else if (i < M_NODES) { xi = node_loc[(i - 1) * 2]; yi = node_loc[(i - 1) * 2 + 1]; }
    __syncthreads();
    uint64_t m = 0;
#pragma unroll
    for (int b = 0; b < 64; ++b) {
#pragma clang fp contract(off)
        float dx = xi - cand[b].x;
        float dy = yi - cand[b].y;
        float xx = dx * dx;
        float yy = dy * dy;
        float d2 = xx + yy;
        if (sqrtf(d2) <= THRESH) m |= (1ull << b);
    }
    if (i < M_NODES) A[(size_t)i * NW + w] = m;
}

// CSR build: per node, deterministic-order neighbor index list from the bitmask.
// 64 threads/block; thread w owns word w; prefix offsets via serial scan (cheap).
__global__ void csr_kernel(const uint64_t* __restrict__ A,
                           int* __restrict__ nbr, int* __restrict__ deg) {
    __shared__ int cnts[64];
    __shared__ int offs[65];
    int i = blockIdx.x, tid = threadIdx.x;
    uint64_t m = (tid < NW) ? A[(size_t)i * NW + tid] : 0ull;
    cnts[tid] = __popcll(m);
    __syncthreads();
    if (tid == 0) {
        int s = 0;
        for (int w = 0; w < 64; ++w) { offs[w] = s; s += cnts[w]; }
        offs[64] = s;
        deg[i] = s;
    }
    __syncthreads();
    int o = offs[tid];
    int base = tid * 64;
    while (m) {
        int b = __builtin_ctzll(m);
        if (o < CAP) nbr[(size_t)i * CAP + o] = base + b;
        ++o;
        m &= m - 1;
    }
}

// fv_1[i] = sum_{j in N(i)} fv_0[j]. 4 groups x 64 lanes x float2.
__global__ void fv1_kernel(const int* __restrict__ nbr, const int* __restrict__ deg,
                           const float* __restrict__ fv0, float* __restrict__ fv1) {
    __shared__ int slist[CAP];
    __shared__ float2 part[4][64];
    int i = blockIdx.x, tid = threadIdx.x;
    int n1 = deg[i]; if (n1 > CAP) n1 = CAP;
    if (tid < CAP) slist[tid] = (tid < n1) ? nbr[(size_t)i * CAP + tid] : 0;
    __syncthreads();
    int lane = tid & 63, g = tid >> 6;
    const float2* fv0v = (const float2*)fv0;
    float2 acc = {0.f, 0.f};
    int l = g;
    for (; l + 4 < n1; l += 8) {
        float2 v0 = fv0v[(size_t)slist[l] * 64 + lane];
        float2 v1 = fv0v[(size_t)slist[l + 4] * 64 + lane];
        acc.x += v0.x; acc.y += v0.y;
        acc.x += v1.x; acc.y += v1.y;
    }
    if (l < n1) {
        float2 v0 = fv0v[(size_t)slist[l] * 64 + lane];
        acc.x += v0.x; acc.y += v0.y;
    }
    part[g][lane] = acc;
    __syncthreads();
    if (g == 0) {
        float2 a = part[0][lane], b = part[1][lane], c = part[2][lane], d = part[3][lane];
        float2 r = { a.x + b.x + c.x + d.x, a.y + b.y + c.y + d.y };
        ((float2*)fv1)[(size_t)i * 64 + lane] = r;
    }
}

// fv_2[i] = sum_{j in M2(i)} popcount(M2_i & A_j) * fv_1[j]
//   M2 row built in-block (OR of neighbor A-rows);
//   counts via CSR bit-tests against LDS m2row;
//   weighted sum: 4 groups x float2, 2-way unrolled.
__global__ void fv2_kernel(const uint64_t* __restrict__ A,
                           const int* __restrict__ nbr, const int* __restrict__ deg,
                           const float* __restrict__ fv1, float* __restrict__ out) {
    __shared__ uint64_t m2part[4][64];
    __shared__ uint64_t m2row[64];
    __shared__ int list1[CAP];
    __shared__ int list2[MAXJ];
    __shared__ float cnt[MAXJ];
    __shared__ float2 part[4][64];
    __shared__ int cnts[64];
    __shared__ int offs[65];

    int i = blockIdx.x, tid = threadIdx.x;
    int lane = tid & 63, g = tid >> 6;
    int n1 = deg[i]; if (n1 > CAP) n1 = CAP;
    if (tid < CAP) list1[tid] = (tid < n1) ? nbr[(size_t)i * CAP + tid] : 0;
    __syncthreads();

    // M2 row i = OR over j in N(i) of A row j (coalesced 504B rows).
    uint64_t o = 0;
    for (int l = g; l < n1; l += 4)
        o |= (lane < NW) ? A[(size_t)list1[l] * NW + lane] : 0ull;
    m2part[g][lane] = o;
    __syncthreads();
    if (g == 0) {
        uint64_t w = m2part[0][lane] | m2part[1][lane] | m2part[2][lane] | m2part[3][lane];
        m2row[lane] = w;
        cnts[lane] = __popcll(w);
    }
    __syncthreads();
    if (tid == 0) {
        int s = 0;
        for (int w = 0; w < 64; ++w) { offs[w] = s; s += cnts[w]; }
        offs[64] = s;
    }
    __syncthreads();
    int n2 = offs[64]; if (n2 > MAXJ) n2 = MAXJ;

    // deterministic enumerate of M2(i)
    if (g == 0) {
        uint64_t m = m2row[lane];
        int oo = offs[lane], base = lane * 64;
        while (m) {
            int b = __builtin_ctzll(m);
            if (oo < MAXJ) list2[oo] = base + b;
            ++oo;
            m &= m - 1;
        }
    }
    __syncthreads();

    // counts: c_j = # of k in N(j) with bit k set in m2row (exact ints)
    for (int l = tid; l < n2; l += 256) {
        int j = list2[l];
        int dj = deg[j]; if (dj > CAP) dj = CAP;
        const int* nj = nbr + (size_t)j * CAP;
        int c = 0;
        for (int k = 0; k < dj; ++k) {
            int u = nj[k];
            c += (int)((m2row[u >> 6] >> (u & 63)) & 1ull);
        }
        cnt[l] = (float)c;
    }
    __syncthreads();

    // weighted sum of fv1 rows
    const float2* fv1v = (const float2*)fv1;
    float2 acc = {0.f, 0.f};
    int l = g;
    for (; l + 4 < n2; l += 8) {
        float  c0 = cnt[l];     float2 v0 = fv1v[(size_t)list2[l] * 64 + lane];
        float  c1 = cnt[l + 4]; float2 v1 = fv1v[(size_t)list2[l + 4] * 64 + lane];
        acc.x = fmaf(c0, v0.x, acc.x); acc.y = fmaf(c0, v0.y, acc.y);
        acc.x = fmaf(c1, v1.x, acc.x); acc.y = fmaf(c1, v1.y, acc.y);
    }
    if (l < n2) {
        float c0 = cnt[l]; float2 v0 = fv1v[(size_t)list2[l] * 64 + lane];
        acc.x = fmaf(c0, v0.x, acc.x); acc.y = fmaf(c0, v0.y, acc.y);
    }
    part[g][lane] = acc;
    __syncthreads();
    if (g == 0) {
        float2 a = part[0][lane], b = part[1][lane], c = part[2][lane], d = part[3][lane];
        float2 r = { a.x + b.x + c.x + d.x, a.y + b.y + c.y + d.y };
        ((float2*)out)[(size_t)i * 64 + lane] = r;
    }
}

extern "C" void kernel_launch(void* const* d_in, const int* in_sizes, int n_in,
                              void* d_out, int out_size, void* d_ws, size_t ws_size,
                              hipStream_t stream) {
    const float* node_loc = (const float*)d_in[0];  // [4000,2]
    const float* td       = (const float*)d_in[1];  // [4000,1]
    const float* depot    = (const float*)d_in[2];  // [1,2]
    const float* W0w      = (const float*)d_in[3];  // [128,3]
    const float* W0b      = (const float*)d_in[4];  // [128]
    float* out = (float*)d_out;                     // [4001,128]

    char* base = (char*)d_ws;
    size_t off = 0;
    auto carve = [&](size_t bytes) {
        char* p = base + off;
        off = (off + bytes + 511) & ~(size_t)511;
        return p;
    };
    uint64_t* A   = (uint64_t*)carve((size_t)M_NODES * NW * sizeof(uint64_t));  // ~2.0 MB
    float*    fv0 = (float*)   carve((size_t)M_NODES * DIM * sizeof(float));    // ~2.0 MB
    float*    fv1 = (float*)   carve((size_t)M_NODES * DIM * sizeof(float));    // ~2.0 MB
    int*      nbr = (int*)     carve((size_t)M_NODES * CAP * sizeof(int));      // ~1.5 MB
    int*      deg = (int*)     carve((size_t)M_NODES * sizeof(int));            // 16 KB

    fv0_kernel<<<(M_NODES * DIM + 255) / 256, 256, 0, stream>>>(node_loc, td, depot, W0w, W0b, fv0);
    dim3 agrid((M_NODES + 255) / 256, NW);
    adj_kernel<<<agrid, 256, 0, stream>>>(node_loc, depot, A);
    csr_kernel<<<M_NODES, 64, 0, stream>>>(A, nbr, deg);
    fv1_kernel<<<M_NODES, 256, 0, stream>>>(nbr, deg, fv0, fv1);
    fv2_kernel<<<M_NODES, 256, 0, stream>>>(A, nbr, deg, fv1, out);
}

// Round 4
// 106.308 us; speedup vs baseline: 1.6426x; 1.0518x over previous
//
#include <hip/hip_runtime.h>
#include <stdint.h>

#define M_NODES 4001
#define NW 63            // ceil(4001/64) bitmask words per row
#define DIM 128
#define THRESH 0.04f
#define MAXJ 512         // cap on |M2(i)| (expected ~80, tail tiny)
#define CAP 96           // cap on degree (expected ~21)

// ---------- fv_0 = relu([loc, td] @ W0^T + b), flat over (node, dim) ----------
__global__ void fv0_kernel(const float* __restrict__ node_loc,
                           const float* __restrict__ td,
                           const float* __restrict__ depot,
                           const float* __restrict__ W0w,
                           const float* __restrict__ W0b,
                           float* __restrict__ fv0) {
    int idx = blockIdx.x * blockDim.x + threadIdx.x;
    if (idx >= M_NODES * DIM) return;
    int i = idx >> 7;
    int d = idx & (DIM - 1);
    float lx, ly, t;
    if (i == 0) { lx = depot[0]; ly = depot[1]; t = 0.f; }
    else { lx = node_loc[(i - 1) * 2]; ly = node_loc[(i - 1) * 2 + 1]; t = td[i - 1]; }
    float v = fmaf(lx, W0w[d * 3 + 0], fmaf(ly, W0w[d * 3 + 1], fmaf(t, W0w[d * 3 + 2], W0b[d])));
    fv0[idx] = v > 0.f ? v : 0.f;
}

// ---------- adjacency bitmask rows ----------
// blockIdx.x = 256-row group, blockIdx.y = word w. LDS candidate tile,
// wave-uniform broadcast reads. Predicate bit-matches numpy:
// d2 = dx*dx + dy*dy (contraction off), correctly-rounded sqrtf, <= 0.04f.
__global__ void adj_kernel(const float* __restrict__ node_loc,
                           const float* __restrict__ depot,
                           uint64_t* __restrict__ A) {
    __shared__ float2 cand[64];
    int w = blockIdx.y;
    int tid = threadIdx.x;
    if (tid < 64) {
        int j = w * 64 + tid;
        float2 c;
        if (j == 0) { c.x = depot[0]; c.y = depot[1]; }
        else if (j < M_NODES) { c.x = node_loc[(j - 1) * 2]; c.y = node_loc[(j - 1) * 2 + 1]; }
        else { c.x = 1e9f; c.y = 1e9f; }
        cand[tid] = c;
    }
    int i = blockIdx.x * blockDim.x + tid;
    float xi = 0.f, yi = 0.f;
    if (i == 0) { xi = depot[0]; yi = depot[1]; }
    else if (i < M_NODES) { xi = node_loc[(i - 1) * 2]; yi = node_loc[(i - 1) * 2 + 1]; }
    __syncthreads();
    uint64_t m = 0;
#pragma unroll
    for (int b = 0; b < 64; ++b) {
#pragma clang fp contract(off)
        float dx = xi - cand[b].x;
        float dy = yi - cand[b].y;
        float xx = dx * dx;
        float yy = dy * dy;
        float d2 = xx + yy;
        if (sqrtf(d2) <= THRESH) m |= (1ull << b);
    }
    if (i < M_NODES) A[(size_t)i * NW + w] = m;
}

// 6-step inclusive shfl scan over 64 lanes; returns inclusive sum for this lane.
__device__ __forceinline__ int wave64_incl_scan(int v, int lane) {
#pragma unroll
    for (int d = 1; d < 64; d <<= 1) {
        int n = __shfl_up(v, d, 64);
        if (lane >= d) v += n;
    }
    return v;
}

// ---------- fused CSR build + fv_1 ----------
// wave 0: load A row, shfl-scan offsets, emit deterministic neighbor list
// (LDS + global nbr/deg for fv2). All 256 threads: fv1[i] = sum fv0[j],
// 8 groups x 32 lanes x float4.
__global__ void fv1csr_kernel(const uint64_t* __restrict__ A,
                              const float* __restrict__ fv0,
                              int* __restrict__ nbr, int* __restrict__ deg,
                              float* __restrict__ fv1) {
    __shared__ int slist[CAP];
    __shared__ float4 part[8][32];
    __shared__ int snn;
    int i = blockIdx.x, tid = threadIdx.x;
    if (tid < 64) {
        uint64_t m = (tid < NW) ? A[(size_t)i * NW + tid] : 0ull;
        int c = __popcll(m);
        int incl = wave64_incl_scan(c, tid);
        int oo = incl - c;
        int base = tid * 64;
        while (m) {
            int b = __builtin_ctzll(m);
            if (oo < CAP) { slist[oo] = base + b; nbr[(size_t)i * CAP + oo] = base + b; }
            ++oo;
            m &= m - 1;
        }
        if (tid == 63) {
            int tot = incl < CAP ? incl : CAP;
            deg[i] = tot;
            snn = tot;
        }
    }
    __syncthreads();
    int n1 = snn;
    int lane = tid & 31, g = tid >> 5;
    const float4* fv0v = (const float4*)fv0;   // row = 32 float4
    float4 acc = {0.f, 0.f, 0.f, 0.f};
    for (int l = g; l < n1; l += 8) {
        float4 v = fv0v[(size_t)slist[l] * 32 + lane];
        acc.x += v.x; acc.y += v.y; acc.z += v.z; acc.w += v.w;
    }
    part[g][lane] = acc;
    __syncthreads();
    if (tid < 32) {
        float4 s = part[0][tid];
#pragma unroll
        for (int gg = 1; gg < 8; ++gg) {
            float4 p = part[gg][tid];
            s.x += p.x; s.y += p.y; s.z += p.z; s.w += p.w;
        }
        ((float4*)fv1)[(size_t)i * 32 + tid] = s;
    }
}

// ---------- fv_2 ----------
// fv2[i] = sum_{j in M2(i)} |M2(i) ∩ N(j)| * fv1[j], M2 row built in-block.
__global__ void fv2_kernel(const uint64_t* __restrict__ A,
                           const int* __restrict__ nbr, const int* __restrict__ deg,
                           const float* __restrict__ fv1, float* __restrict__ out) {
    __shared__ uint64_t m2part[4][64];
    __shared__ uint64_t m2row[64];
    __shared__ int list1[CAP];
    __shared__ int list2[MAXJ];
    __shared__ float cnt[MAXJ];
    __shared__ float4 part[8][32];
    __shared__ int snn2;

    int i = blockIdx.x, tid = threadIdx.x;
    int lane64 = tid & 63, g4 = tid >> 6;
    int n1 = deg[i];
    if (tid < CAP) list1[tid] = (tid < n1) ? nbr[(size_t)i * CAP + tid] : 0;
    __syncthreads();

    // M2 row i = OR over j in N(i) of A row j (coalesced 504B rows).
    uint64_t o = 0;
    for (int l = g4; l < n1; l += 4)
        o |= (lane64 < NW) ? A[(size_t)list1[l] * NW + lane64] : 0ull;
    m2part[g4][lane64] = o;
    __syncthreads();

    // wave 0: OR-combine, shfl-scan, deterministic enumerate of M2(i)
    if (tid < 64) {
        uint64_t m = m2part[0][tid] | m2part[1][tid] | m2part[2][tid] | m2part[3][tid];
        m2row[tid] = m;
        int c = __popcll(m);
        int incl = wave64_incl_scan(c, tid);
        int oo = incl - c;
        int base = tid * 64;
        while (m) {
            int b = __builtin_ctzll(m);
            if (oo < MAXJ) list2[oo] = base + b;
            ++oo;
            m &= m - 1;
        }
        if (tid == 63) snn2 = incl < MAXJ ? incl : MAXJ;
    }
    __syncthreads();
    int n2 = snn2;

    // counts: c_j = # of k in N(j) with bit k in m2row (exact small ints)
    for (int l = tid; l < n2; l += 256) {
        int j = list2[l];
        int dj = deg[j];
        const int* nj = nbr + (size_t)j * CAP;
        int c = 0;
        for (int k = 0; k < dj; ++k) {
            int u = nj[k];
            c += (int)((m2row[u >> 6] >> (u & 63)) & 1ull);
        }
        cnt[l] = (float)c;
    }
    __syncthreads();

    // weighted sum of fv1 rows: 8 groups x 32 lanes x float4
    int lane = tid & 31, g = tid >> 5;
    const float4* fv1v = (const float4*)fv1;
    float4 acc = {0.f, 0.f, 0.f, 0.f};
    for (int l = g; l < n2; l += 8) {
        float c0 = cnt[l];
        float4 v = fv1v[(size_t)list2[l] * 32 + lane];
        acc.x = fmaf(c0, v.x, acc.x); acc.y = fmaf(c0, v.y, acc.y);
        acc.z = fmaf(c0, v.z, acc.z); acc.w = fmaf(c0, v.w, acc.w);
    }
    part[g][lane] = acc;
    __syncthreads();
    if (tid < 32) {
        float4 s = part[0][tid];
#pragma unroll
        for (int gg = 1; gg < 8; ++gg) {
            float4 p = part[gg][tid];
            s.x += p.x; s.y += p.y; s.z += p.z; s.w += p.w;
        }
        ((float4*)out)[(size_t)i * 32 + tid] = s;
    }
}

extern "C" void kernel_launch(void* const* d_in, const int* in_sizes, int n_in,
                              void* d_out, int out_size, void* d_ws, size_t ws_size,
                              hipStream_t stream) {
    const float* node_loc = (const float*)d_in[0];  // [4000,2]
    const float* td       = (const float*)d_in[1];  // [4000,1]
    const float* depot    = (const float*)d_in[2];  // [1,2]
    const float* W0w      = (const float*)d_in[3];  // [128,3]
    const float* W0b      = (const float*)d_in[4];  // [128]
    float* out = (float*)d_out;                     // [4001,128]

    char* base = (char*)d_ws;
    size_t off = 0;
    auto carve = [&](size_t bytes) {
        char* p = base + off;
        off = (off + bytes + 511) & ~(size_t)511;
        return p;
    };
    uint64_t* A   = (uint64_t*)carve((size_t)M_NODES * NW * sizeof(uint64_t));  // ~2.0 MB
    float*    fv0 = (float*)   carve((size_t)M_NODES * DIM * sizeof(float));    // ~2.0 MB
    float*    fv1 = (float*)   carve((size_t)M_NODES * DIM * sizeof(float));    // ~2.0 MB
    int*      nbr = (int*)     carve((size_t)M_NODES * CAP * sizeof(int));      // ~1.5 MB
    int*      deg = (int*)     carve((size_t)M_NODES * sizeof(int));            // 16 KB

    fv0_kernel<<<(M_NODES * DIM + 255) / 256, 256, 0, stream>>>(node_loc, td, depot, W0w, W0b, fv0);
    dim3 agrid((M_NODES + 255) / 256, NW);
    adj_kernel<<<agrid, 256, 0, stream>>>(node_loc, depot, A);
    fv1csr_kernel<<<M_NODES, 256, 0, stream>>>(A, fv0, nbr, deg, fv1);
    fv2_kernel<<<M_NODES, 256, 0, stream>>>(A, nbr, deg, fv1, out);
}